// Round 8
// baseline (101.734 us; speedup 1.0000x reference)
//
#include <hip/hip_runtime.h>
#include <math.h>

// Problem constants
#define BB 8
#define CC 3
#define DD 24
#define HH 128
#define WW 128
#define HW (HH * WW)
#define OCC 16
#define HOUT 126
#define WOUT 126

// Kernel 1: transpose weights [oc][tap] -> [tap][oc] into d_ws so each tap's
// 16 oc-weights are contiguous (64 B) -> wave-uniform float4 loads become
// s_load_dwordx4/x16 and weights live in SGPRs (v_fmac_f32 takes 1 SGPR op).
__global__ void wtrans_kernel(const float* __restrict__ wt,
                              float* __restrict__ wT) {
  const int i = blockIdx.x * 256 + threadIdx.x;
  if (i < 81 * 16) {
    const int tap = i >> 4;
    const int oc = i & 15;
    wT[i] = wt[oc * 81 + tap];
  }
}

// Load one slice's 3 input rows x 4 columns as 6 named float2 regs.
#define LOADS(P, R)                                                   \
  R##0 = *reinterpret_cast<const float2*>((P));                       \
  R##1 = *reinterpret_cast<const float2*>((P) + 2);                   \
  R##2 = *reinterpret_cast<const float2*>((P) + WW);                  \
  R##3 = *reinterpret_cast<const float2*>((P) + WW + 2);              \
  R##4 = *reinterpret_cast<const float2*>((P) + 2 * WW);              \
  R##5 = *reinterpret_cast<const float2*>((P) + 2 * WW + 2);

// One tap: 16 oc weights (4 float4, wave-uniform -> SGPR), 32 FMAs.
#define TAP16(WP, XA, XB)                                             \
  {                                                                   \
    const float4 wA = *reinterpret_cast<const float4*>((WP) + 0);     \
    const float4 wB = *reinterpret_cast<const float4*>((WP) + 4);     \
    const float4 wC = *reinterpret_cast<const float4*>((WP) + 8);     \
    const float4 wD = *reinterpret_cast<const float4*>((WP) + 12);    \
    y0[0]  = fmaf((XA), wA.x, y0[0]);  y1[0]  = fmaf((XB), wA.x, y1[0]);  \
    y0[1]  = fmaf((XA), wA.y, y0[1]);  y1[1]  = fmaf((XB), wA.y, y1[1]);  \
    y0[2]  = fmaf((XA), wA.z, y0[2]);  y1[2]  = fmaf((XB), wA.z, y1[2]);  \
    y0[3]  = fmaf((XA), wA.w, y0[3]);  y1[3]  = fmaf((XB), wA.w, y1[3]);  \
    y0[4]  = fmaf((XA), wB.x, y0[4]);  y1[4]  = fmaf((XB), wB.x, y1[4]);  \
    y0[5]  = fmaf((XA), wB.y, y0[5]);  y1[5]  = fmaf((XB), wB.y, y1[5]);  \
    y0[6]  = fmaf((XA), wB.z, y0[6]);  y1[6]  = fmaf((XB), wB.z, y1[6]);  \
    y0[7]  = fmaf((XA), wB.w, y0[7]);  y1[7]  = fmaf((XB), wB.w, y1[7]);  \
    y0[8]  = fmaf((XA), wC.x, y0[8]);  y1[8]  = fmaf((XB), wC.x, y1[8]);  \
    y0[9]  = fmaf((XA), wC.y, y0[9]);  y1[9]  = fmaf((XB), wC.y, y1[9]);  \
    y0[10] = fmaf((XA), wC.z, y0[10]); y1[10] = fmaf((XB), wC.z, y1[10]); \
    y0[11] = fmaf((XA), wC.w, y0[11]); y1[11] = fmaf((XB), wC.w, y1[11]); \
    y0[12] = fmaf((XA), wD.x, y0[12]); y1[12] = fmaf((XB), wD.x, y1[12]); \
    y0[13] = fmaf((XA), wD.y, y0[13]); y1[13] = fmaf((XB), wD.y, y1[13]); \
    y0[14] = fmaf((XA), wD.z, y0[14]); y1[14] = fmaf((XB), wD.z, y1[14]); \
    y0[15] = fmaf((XA), wD.w, y0[15]); y1[15] = fmaf((XB), wD.w, y1[15]); \
  }

// One kh row (3 taps) from preloaded row regs Q0..Q3.
#define TG(WP, Q0, Q1, Q2, Q3)                                        \
  TAP16((WP), Q0, Q1)                                                 \
  TAP16((WP) + 16, Q1, Q2)                                            \
  TAP16((WP) + 32, Q2, Q3)

// Whole slice (3 kh rows, 288 FMAs) from the 'c' register set.
#define COMPUTE(S)                                                    \
  {                                                                   \
    const float* wsl = wT + (S) * 144;                                \
    TG(wsl, c0.x, c0.y, c1.x, c1.y);                                  \
    TG(wsl + 48, c2.x, c2.y, c3.x, c3.y);                             \
    TG(wsl + 96, c4.x, c4.y, c5.x, c5.y);                             \
  }

// Kernel 2: 512-thread blocks = 8 waves; wave g handles dz sub-range
// ({3,3,3,3,3,3,2,2}). Each lane: 2 adjacent output columns (w0 = 2*lane),
// all 16 channels. Weights via wave-uniform s_loads (SGPRs). 1-D grid with
// b = wgid&7 pins each batch to one XCD (round 7: FETCH 130->18.5 MB).
// ROUND 8 CHANGE: slice-level x-register double-buffering — prefetch slice
// s+1's 6 float2 rows into 'n' regs while slice s's 288 FMAs run, rotate at
// slice end. One vmcnt wait per 288 FMA-issues instead of 3 waits per 96.
__global__ __launch_bounds__(512) void conv_min_softmax_kernel(
    const float* __restrict__ x, const float* __restrict__ wT,
    float* __restrict__ out) {
  __shared__ float sm[4][OCC][WOUT];  // two-stage combine buffers

  const int tid = threadIdx.x;
  const int lane = tid & 63;
  const int g = tid >> 6;  // wave id 0..7
  const int wg = blockIdx.x;
  const int b = wg & 7;    // XCD selector: all h-blocks of batch b -> XCD b
  const int h = wg >> 3;   // 0..125
  const bool active = (lane < 63);          // 63 lanes cover w0 = 0..124
  const int w0 = 2 * (active ? lane : 62);  // clamp inactive lane's addresses

  // dz ranges per wave: waves 0..5 -> 3 dz each (start 3g), waves 6,7 -> 2 dz
  const int dz0 = (g < 6) ? 3 * g : 18 + 2 * (g - 6);
  const int ndz = (g < 6) ? 3 : 2;

  // Pointer at (b, c=0, depth=dz0, h, w0)
  const float* xd =
      x + (((size_t)b * CC * DD + dz0) * HH + h) * (size_t)WW + w0;

  float mn0[OCC], mn1[OCC];
#pragma unroll
  for (int oc = 0; oc < OCC; ++oc) { mn0[oc] = INFINITY; mn1[oc] = INFINITY; }

#pragma clang loop unroll(disable)
  for (int i = 0; i < ndz; ++i) {
    float y0[OCC], y1[OCC];
#pragma unroll
    for (int oc = 0; oc < OCC; ++oc) { y0[oc] = 0.f; y1[oc] = 0.f; }

    const float* ps = xd;  // slice (c=0, kd=0)
    float2 c0, c1, c2, c3, c4, c5;
    float2 n0, n1, n2, n3, n4, n5;
    LOADS(ps, c)  // slice 0

#pragma clang loop unroll(disable)
    for (int s = 0; s < 8; ++s) {
      // advance: kd step = HW; (c,2)->(c+1,0) step = (DD-2)*HW
      const float* psn =
          ps + ((s == 2 || s == 5) ? (size_t)(DD - 2) * HW : (size_t)HW);
      LOADS(psn, n)   // prefetch slice s+1 (no wait until rotation below)
      COMPUTE(s)      // 288 FMAs on current regs
      c0 = n0; c1 = n1; c2 = n2; c3 = n3; c4 = n4; c5 = n5;
      ps = psn;
    }
    COMPUTE(8)  // last slice, no prefetch

#pragma unroll
    for (int oc = 0; oc < OCC; ++oc) {
      mn0[oc] = fminf(mn0[oc], y0[oc]);
      mn1[oc] = fminf(mn1[oc], y1[oc]);
    }
    xd += HW;  // next depth
  }

  // Stage 1: waves 4..7 publish partial mins into buffers 0..3.
  // Layout [oc][w] with lanes at w0=2*lane -> 2-way bank aliasing (free).
  if (g >= 4 && active) {
#pragma unroll
    for (int oc = 0; oc < OCC; ++oc) {
      sm[g - 4][oc][w0] = mn0[oc];
      sm[g - 4][oc][w0 + 1] = mn1[oc];
    }
  }
  __syncthreads();

  if (g < 4 && active) {
    // Wave g merges buffer g (each lane touches only its own columns, so the
    // stage-2 reuse of buffers 1..3 below is hazard-free).
#pragma unroll
    for (int oc = 0; oc < OCC; ++oc) {
      mn0[oc] = fminf(mn0[oc], sm[g][oc][w0]);
      mn1[oc] = fminf(mn1[oc], sm[g][oc][w0 + 1]);
    }
    // Stage 2: waves 1..3 publish merged mins into buffers 1..3.
    if (g > 0) {
#pragma unroll
      for (int oc = 0; oc < OCC; ++oc) {
        sm[g][oc][w0] = mn0[oc];
        sm[g][oc][w0 + 1] = mn1[oc];
      }
    }
  }
  __syncthreads();

  if (g == 0 && active) {
#pragma unroll
    for (int oc = 0; oc < OCC; ++oc) {
      mn0[oc] = fminf(fminf(mn0[oc], sm[1][oc][w0]),
                      fminf(sm[2][oc][w0], sm[3][oc][w0]));
      mn1[oc] = fminf(fminf(mn1[oc], sm[1][oc][w0 + 1]),
                      fminf(sm[2][oc][w0 + 1], sm[3][oc][w0 + 1]));
    }
    float mx0 = mn0[0], mx1 = mn1[0];
#pragma unroll
    for (int oc = 1; oc < OCC; ++oc) {
      mx0 = fmaxf(mx0, mn0[oc]);
      mx1 = fmaxf(mx1, mn1[oc]);
    }
    float e0[OCC], e1[OCC];
    float s0 = 0.f, s1 = 0.f;
#pragma unroll
    for (int oc = 0; oc < OCC; ++oc) {
      e0[oc] = __expf(mn0[oc] - mx0); s0 += e0[oc];
      e1[oc] = __expf(mn1[oc] - mx1); s1 += e1[oc];
    }
    const float i0 = 1.f / s0;
    const float i1 = 1.f / s1;

    float* ob = out + ((size_t)b * OCC * HOUT + h) * (size_t)WOUT + w0;
    const size_t os = (size_t)HOUT * WOUT;
#pragma unroll
    for (int oc = 0; oc < OCC; ++oc) {
      float2 v;
      v.x = e0[oc] * i0;
      v.y = e1[oc] * i1;
      *reinterpret_cast<float2*>(ob + oc * os) = v;  // w0 even -> 8B aligned
    }
  }
}

extern "C" void kernel_launch(void* const* d_in, const int* in_sizes, int n_in,
                              void* d_out, int out_size, void* d_ws, size_t ws_size,
                              hipStream_t stream) {
  const float* x = (const float*)d_in[0];
  const float* wt = (const float*)d_in[1];
  float* out = (float*)d_out;
  float* wT = (float*)d_ws;  // 81*16 floats = 5184 B scratch

  wtrans_kernel<<<dim3(6), dim3(256), 0, stream>>>(wt, wT);

  dim3 grid(1008);          // 1-D: wgid&7 = batch = XCD, wgid>>3 = h
  dim3 block(512, 1, 1);    // 8 waves = 8 dz-groups, Wtile=2
  conv_min_softmax_kernel<<<grid, block, 0, stream>>>(x, wT, out);
}

// Round 9
// 87.827 us; speedup vs baseline: 1.1584x; 1.1584x over previous
//
#include <hip/hip_runtime.h>
#include <math.h>

// Problem constants
#define BB 8
#define CC 3
#define DD 24
#define HH 128
#define WW 128
#define HW (HH * WW)
#define OCC 16
#define HOUT 126
#define WOUT 126

// Kernel 1: transpose weights [oc][tap] -> [tap][oc] into d_ws so each tap's
// 16 oc-weights are contiguous (64 B) -> wave-uniform float4 loads become
// s_load_dwordx4/x16 and weights live in SGPRs (v_fmac_f32 takes 1 SGPR op).
__global__ void wtrans_kernel(const float* __restrict__ wt,
                              float* __restrict__ wT) {
  const int i = blockIdx.x * 256 + threadIdx.x;
  if (i < 81 * 16) {
    const int tap = i >> 4;
    const int oc = i & 15;
    wT[i] = wt[oc * 81 + tap];
  }
}

// Process CN consecutive depths for one wave: loops slice -> kh-row -> dz.
// KEY (round 9): the 48 weight dwords per (slice,kh) are s_loaded ONCE and
// feed CN depths' worth of FMAs (96*CN), instead of being re-fetched every
// depth (rounds 5-8: 27 lgkm waits/dz in lockstep across all waves = the
// ~40% stall). All array indices compile-time (full unroll over dzi/kw).
template <int CN>
__device__ __forceinline__ void conv_chunk(const float* __restrict__ xbase,
                                           const float* __restrict__ wT,
                                           float* __restrict__ mn0,
                                           float* __restrict__ mn1) {
  float y0[CN][OCC], y1[CN][OCC];
#pragma unroll
  for (int d = 0; d < CN; ++d)
#pragma unroll
    for (int oc = 0; oc < OCC; ++oc) { y0[d][oc] = 0.f; y1[d][oc] = 0.f; }

  const float* ps = xbase;  // slice (c=0, kd=0) at depth dz0
#pragma clang loop unroll(disable)
  for (int s = 0; s < 9; ++s) {  // slice = (c, kd)
    const float* wsl = wT + s * 144;
#pragma clang loop unroll(disable)
    for (int tg = 0; tg < 3; ++tg) {  // kh row
      const float* row = ps + tg * WW;
      // Issue all CN depths' x-rows (4 floats each) before any FMA.
      float2 q[CN][2];
#pragma unroll
      for (int d = 0; d < CN; ++d) {
        q[d][0] = *reinterpret_cast<const float2*>(row + (size_t)d * HW);
        q[d][1] = *reinterpret_cast<const float2*>(row + (size_t)d * HW + 2);
      }
      const float* wp = wsl + tg * 48;  // wave-uniform -> SGPRs
#pragma unroll
      for (int kw = 0; kw < 3; ++kw) {
        const float4 wA = *reinterpret_cast<const float4*>(wp + kw * 16 + 0);
        const float4 wB = *reinterpret_cast<const float4*>(wp + kw * 16 + 4);
        const float4 wC = *reinterpret_cast<const float4*>(wp + kw * 16 + 8);
        const float4 wD = *reinterpret_cast<const float4*>(wp + kw * 16 + 12);
#pragma unroll
        for (int d = 0; d < CN; ++d) {
          const float xa = (kw == 0) ? q[d][0].x : (kw == 1) ? q[d][0].y : q[d][1].x;
          const float xb = (kw == 0) ? q[d][0].y : (kw == 1) ? q[d][1].x : q[d][1].y;
          y0[d][0]  = fmaf(xa, wA.x, y0[d][0]);  y1[d][0]  = fmaf(xb, wA.x, y1[d][0]);
          y0[d][1]  = fmaf(xa, wA.y, y0[d][1]);  y1[d][1]  = fmaf(xb, wA.y, y1[d][1]);
          y0[d][2]  = fmaf(xa, wA.z, y0[d][2]);  y1[d][2]  = fmaf(xb, wA.z, y1[d][2]);
          y0[d][3]  = fmaf(xa, wA.w, y0[d][3]);  y1[d][3]  = fmaf(xb, wA.w, y1[d][3]);
          y0[d][4]  = fmaf(xa, wB.x, y0[d][4]);  y1[d][4]  = fmaf(xb, wB.x, y1[d][4]);
          y0[d][5]  = fmaf(xa, wB.y, y0[d][5]);  y1[d][5]  = fmaf(xb, wB.y, y1[d][5]);
          y0[d][6]  = fmaf(xa, wB.z, y0[d][6]);  y1[d][6]  = fmaf(xb, wB.z, y1[d][6]);
          y0[d][7]  = fmaf(xa, wB.w, y0[d][7]);  y1[d][7]  = fmaf(xb, wB.w, y1[d][7]);
          y0[d][8]  = fmaf(xa, wC.x, y0[d][8]);  y1[d][8]  = fmaf(xb, wC.x, y1[d][8]);
          y0[d][9]  = fmaf(xa, wC.y, y0[d][9]);  y1[d][9]  = fmaf(xb, wC.y, y1[d][9]);
          y0[d][10] = fmaf(xa, wC.z, y0[d][10]); y1[d][10] = fmaf(xb, wC.z, y1[d][10]);
          y0[d][11] = fmaf(xa, wC.w, y0[d][11]); y1[d][11] = fmaf(xb, wC.w, y1[d][11]);
          y0[d][12] = fmaf(xa, wD.x, y0[d][12]); y1[d][12] = fmaf(xb, wD.x, y1[d][12]);
          y0[d][13] = fmaf(xa, wD.y, y0[d][13]); y1[d][13] = fmaf(xb, wD.y, y1[d][13]);
          y0[d][14] = fmaf(xa, wD.z, y0[d][14]); y1[d][14] = fmaf(xb, wD.z, y1[d][14]);
          y0[d][15] = fmaf(xa, wD.w, y0[d][15]); y1[d][15] = fmaf(xb, wD.w, y1[d][15]);
        }
      }
    }
    // advance slice: kd step = HW; (c,2)->(c+1,0) step = (DD-2)*HW
    ps += (s == 2 || s == 5) ? (size_t)(DD - 2) * HW : (size_t)HW;
  }

#pragma unroll
  for (int d = 0; d < CN; ++d)
#pragma unroll
    for (int oc = 0; oc < OCC; ++oc) {
      mn0[oc] = fminf(mn0[oc], y0[d][oc]);
      mn1[oc] = fminf(mn1[oc], y1[d][oc]);
    }
}

// Kernel 2: 256-thread blocks = 4 waves; wave g covers dz {0-5,6-11,12-16,
// 17-21} as chunks 3+3 (g<2) or 3+2 (g>=2). Each lane: 2 adjacent output
// columns (w0 = 2*lane), all 16 channels. 1-D grid, b = wgid&7 pins each
// batch to one XCD (round 7: FETCH 130->18.5 MB). Waves 1..3 publish partial
// mins to LDS; wave 0 merges + softmax + stores.
__global__ __launch_bounds__(256) void conv_min_softmax_kernel(
    const float* __restrict__ x, const float* __restrict__ wT,
    float* __restrict__ out) {
  __shared__ float sm[3][OCC][WOUT];  // 24.2 KB -> 3 blocks/CU fit easily

  const int tid = threadIdx.x;
  const int lane = tid & 63;
  const int g = tid >> 6;  // wave id 0..3
  const int wg = blockIdx.x;
  const int b = wg & 7;    // XCD selector: all h-blocks of batch b -> XCD b
  const int h = wg >> 3;   // 0..125
  const bool active = (lane < 63);          // 63 lanes cover w0 = 0..124
  const int w0 = 2 * (active ? lane : 62);  // clamp inactive lane's addresses

  // dz ranges per wave: {0-5, 6-11, 12-16, 17-21}
  const int dz0 = (g < 2) ? 6 * g : 12 + 5 * (g - 2);

  const float* xw =
      x + (((size_t)b * CC * DD + dz0) * HH + h) * (size_t)WW + w0;

  float mn0[OCC], mn1[OCC];
#pragma unroll
  for (int oc = 0; oc < OCC; ++oc) { mn0[oc] = INFINITY; mn1[oc] = INFINITY; }

  conv_chunk<3>(xw, wT, mn0, mn1);
  if (g < 2) {
    conv_chunk<3>(xw + 3 * (size_t)HW, wT, mn0, mn1);
  } else {
    conv_chunk<2>(xw + 3 * (size_t)HW, wT, mn0, mn1);
  }

  // Waves 1..3 publish partial mins ([oc][w] layout: lanes at w0=2*lane ->
  // 2-way bank aliasing, free).
  if (g > 0 && active) {
#pragma unroll
    for (int oc = 0; oc < OCC; ++oc) {
      sm[g - 1][oc][w0] = mn0[oc];
      sm[g - 1][oc][w0 + 1] = mn1[oc];
    }
  }
  __syncthreads();

  if (g == 0 && active) {
#pragma unroll
    for (int oc = 0; oc < OCC; ++oc) {
      mn0[oc] = fminf(fminf(mn0[oc], sm[0][oc][w0]),
                      fminf(sm[1][oc][w0], sm[2][oc][w0]));
      mn1[oc] = fminf(fminf(mn1[oc], sm[0][oc][w0 + 1]),
                      fminf(sm[1][oc][w0 + 1], sm[2][oc][w0 + 1]));
    }
    float mx0 = mn0[0], mx1 = mn1[0];
#pragma unroll
    for (int oc = 1; oc < OCC; ++oc) {
      mx0 = fmaxf(mx0, mn0[oc]);
      mx1 = fmaxf(mx1, mn1[oc]);
    }
    float e0[OCC], e1[OCC];
    float s0 = 0.f, s1 = 0.f;
#pragma unroll
    for (int oc = 0; oc < OCC; ++oc) {
      e0[oc] = __expf(mn0[oc] - mx0); s0 += e0[oc];
      e1[oc] = __expf(mn1[oc] - mx1); s1 += e1[oc];
    }
    const float i0 = 1.f / s0;
    const float i1 = 1.f / s1;

    float* ob = out + ((size_t)b * OCC * HOUT + h) * (size_t)WOUT + w0;
    const size_t os = (size_t)HOUT * WOUT;
#pragma unroll
    for (int oc = 0; oc < OCC; ++oc) {
      float2 v;
      v.x = e0[oc] * i0;
      v.y = e1[oc] * i1;
      *reinterpret_cast<float2*>(ob + oc * os) = v;  // w0 even -> 8B aligned
    }
  }
}

extern "C" void kernel_launch(void* const* d_in, const int* in_sizes, int n_in,
                              void* d_out, int out_size, void* d_ws, size_t ws_size,
                              hipStream_t stream) {
  const float* x = (const float*)d_in[0];
  const float* wt = (const float*)d_in[1];
  float* out = (float*)d_out;
  float* wT = (float*)d_ws;  // 81*16 floats = 5184 B scratch

  wtrans_kernel<<<dim3(6), dim3(256), 0, stream>>>(wt, wT);

  dim3 grid(1008);          // 1-D: wgid&7 = batch = XCD, wgid>>3 = h
  dim3 block(256, 1, 1);    // 4 waves, dz chunks 3+3 / 3+2, Wtile=2
  conv_min_softmax_kernel<<<grid, block, 0, stream>>>(x, wT, out);
}

// Round 10
// 83.727 us; speedup vs baseline: 1.2151x; 1.0490x over previous
//
#include <hip/hip_runtime.h>
#include <math.h>

// Problem constants
#define BB 8
#define CC 3
#define DD 24
#define HH 128
#define WW 128
#define HW (HH * WW)
#define OCC 16
#define HOUT 126
#define WOUT 126

// Kernel 1: transpose weights [oc][tap] -> [tap][oc] into d_ws so each tap's
// 16 oc-weights are contiguous (64 B) -> wave-uniform float4 loads become
// s_load_dwordx4/x16 and weights live in SGPRs (v_fmac_f32 takes 1 SGPR op).
__global__ void wtrans_kernel(const float* __restrict__ wt,
                              float* __restrict__ wT) {
  const int i = blockIdx.x * 256 + threadIdx.x;
  if (i < 81 * 16) {
    const int tap = i >> 4;
    const int oc = i & 15;
    wT[i] = wt[oc * 81 + tap];
  }
}

// Process CN consecutive depths for one wave.
// Round 9: weights s_loaded once per (slice,kh) feed CN depths (3x fewer
// lgkm waits). ROUND 10: x-loads hoisted from kh-row level to SLICE level —
// all CN*3 rows (CN*6 float2) issued in one burst, then the full 288*CN-FMA
// slice body runs -> one vmcnt wait per 1728 issue-cycles instead of three
// per 576 (the r9 residual stall: waits at the head of every FMA block).
// All array indices compile-time (rule #20).
template <int CN>
__device__ __forceinline__ void conv_chunk(const float* __restrict__ xbase,
                                           const float* __restrict__ wT,
                                           float* __restrict__ mn0,
                                           float* __restrict__ mn1) {
  float y0[CN][OCC], y1[CN][OCC];
#pragma unroll
  for (int d = 0; d < CN; ++d)
#pragma unroll
    for (int oc = 0; oc < OCC; ++oc) { y0[d][oc] = 0.f; y1[d][oc] = 0.f; }

  const float* ps = xbase;  // slice (c=0, kd=0) at depth dz0
#pragma clang loop unroll(disable)
  for (int s = 0; s < 9; ++s) {  // slice = (c, kd)
    // Load the whole slice x-tile: CN depths x 3 rows x 4 cols.
    float2 q[CN][3][2];
#pragma unroll
    for (int d = 0; d < CN; ++d) {
#pragma unroll
      for (int r = 0; r < 3; ++r) {
        const float* rp = ps + (size_t)d * HW + r * WW;
        q[d][r][0] = *reinterpret_cast<const float2*>(rp);
        q[d][r][1] = *reinterpret_cast<const float2*>(rp + 2);
      }
    }
    const float* wsl = wT + s * 144;
#pragma unroll
    for (int r = 0; r < 3; ++r) {  // kh row
      const float* wp = wsl + r * 48;  // wave-uniform -> SGPRs
#pragma unroll
      for (int kw = 0; kw < 3; ++kw) {
        const float4 wA = *reinterpret_cast<const float4*>(wp + kw * 16 + 0);
        const float4 wB = *reinterpret_cast<const float4*>(wp + kw * 16 + 4);
        const float4 wC = *reinterpret_cast<const float4*>(wp + kw * 16 + 8);
        const float4 wD = *reinterpret_cast<const float4*>(wp + kw * 16 + 12);
#pragma unroll
        for (int d = 0; d < CN; ++d) {
          const float xa = (kw == 0) ? q[d][r][0].x : (kw == 1) ? q[d][r][0].y : q[d][r][1].x;
          const float xb = (kw == 0) ? q[d][r][0].y : (kw == 1) ? q[d][r][1].x : q[d][r][1].y;
          y0[d][0]  = fmaf(xa, wA.x, y0[d][0]);  y1[d][0]  = fmaf(xb, wA.x, y1[d][0]);
          y0[d][1]  = fmaf(xa, wA.y, y0[d][1]);  y1[d][1]  = fmaf(xb, wA.y, y1[d][1]);
          y0[d][2]  = fmaf(xa, wA.z, y0[d][2]);  y1[d][2]  = fmaf(xb, wA.z, y1[d][2]);
          y0[d][3]  = fmaf(xa, wA.w, y0[d][3]);  y1[d][3]  = fmaf(xb, wA.w, y1[d][3]);
          y0[d][4]  = fmaf(xa, wB.x, y0[d][4]);  y1[d][4]  = fmaf(xb, wB.x, y1[d][4]);
          y0[d][5]  = fmaf(xa, wB.y, y0[d][5]);  y1[d][5]  = fmaf(xb, wB.y, y1[d][5]);
          y0[d][6]  = fmaf(xa, wB.z, y0[d][6]);  y1[d][6]  = fmaf(xb, wB.z, y1[d][6]);
          y0[d][7]  = fmaf(xa, wB.w, y0[d][7]);  y1[d][7]  = fmaf(xb, wB.w, y1[d][7]);
          y0[d][8]  = fmaf(xa, wC.x, y0[d][8]);  y1[d][8]  = fmaf(xb, wC.x, y1[d][8]);
          y0[d][9]  = fmaf(xa, wC.y, y0[d][9]);  y1[d][9]  = fmaf(xb, wC.y, y1[d][9]);
          y0[d][10] = fmaf(xa, wC.z, y0[d][10]); y1[d][10] = fmaf(xb, wC.z, y1[d][10]);
          y0[d][11] = fmaf(xa, wC.w, y0[d][11]); y1[d][11] = fmaf(xb, wC.w, y1[d][11]);
          y0[d][12] = fmaf(xa, wD.x, y0[d][12]); y1[d][12] = fmaf(xb, wD.x, y1[d][12]);
          y0[d][13] = fmaf(xa, wD.y, y0[d][13]); y1[d][13] = fmaf(xb, wD.y, y1[d][13]);
          y0[d][14] = fmaf(xa, wD.z, y0[d][14]); y1[d][14] = fmaf(xb, wD.z, y1[d][14]);
          y0[d][15] = fmaf(xa, wD.w, y0[d][15]); y1[d][15] = fmaf(xb, wD.w, y1[d][15]);
        }
      }
    }
    // advance slice: kd step = HW; (c,2)->(c+1,0) step = (DD-2)*HW
    ps += (s == 2 || s == 5) ? (size_t)(DD - 2) * HW : (size_t)HW;
  }

#pragma unroll
  for (int d = 0; d < CN; ++d)
#pragma unroll
    for (int oc = 0; oc < OCC; ++oc) {
      mn0[oc] = fminf(mn0[oc], y0[d][oc]);
      mn1[oc] = fminf(mn1[oc], y1[d][oc]);
    }
}

// Kernel 2: 256-thread blocks = 4 waves; wave g covers dz {0-5,6-11,12-16,
// 17-21} as chunks 3+3 (g<2) or 3+2 (g>=2). Each lane: 2 adjacent output
// columns (w0 = 2*lane), all 16 channels. 1-D grid, b = wgid&7 pins each
// batch to one XCD (round 7: FETCH 130->18.5 MB). Waves 1..3 publish partial
// mins to LDS; wave 0 merges + softmax + stores.
__global__ __launch_bounds__(256) void conv_min_softmax_kernel(
    const float* __restrict__ x, const float* __restrict__ wT,
    float* __restrict__ out) {
  __shared__ float sm[3][OCC][WOUT];  // 24.2 KB

  const int tid = threadIdx.x;
  const int lane = tid & 63;
  const int g = tid >> 6;  // wave id 0..3
  const int wg = blockIdx.x;
  const int b = wg & 7;    // XCD selector: all h-blocks of batch b -> XCD b
  const int h = wg >> 3;   // 0..125
  const bool active = (lane < 63);          // 63 lanes cover w0 = 0..124
  const int w0 = 2 * (active ? lane : 62);  // clamp inactive lane's addresses

  // dz ranges per wave: {0-5, 6-11, 12-16, 17-21}
  const int dz0 = (g < 2) ? 6 * g : 12 + 5 * (g - 2);

  const float* xw =
      x + (((size_t)b * CC * DD + dz0) * HH + h) * (size_t)WW + w0;

  float mn0[OCC], mn1[OCC];
#pragma unroll
  for (int oc = 0; oc < OCC; ++oc) { mn0[oc] = INFINITY; mn1[oc] = INFINITY; }

  conv_chunk<3>(xw, wT, mn0, mn1);
  if (g < 2) {
    conv_chunk<3>(xw + 3 * (size_t)HW, wT, mn0, mn1);
  } else {
    conv_chunk<2>(xw + 3 * (size_t)HW, wT, mn0, mn1);
  }

  // Waves 1..3 publish partial mins ([oc][w] layout: lanes at w0=2*lane ->
  // 2-way bank aliasing, free).
  if (g > 0 && active) {
#pragma unroll
    for (int oc = 0; oc < OCC; ++oc) {
      sm[g - 1][oc][w0] = mn0[oc];
      sm[g - 1][oc][w0 + 1] = mn1[oc];
    }
  }
  __syncthreads();

  if (g == 0 && active) {
#pragma unroll
    for (int oc = 0; oc < OCC; ++oc) {
      mn0[oc] = fminf(fminf(mn0[oc], sm[0][oc][w0]),
                      fminf(sm[1][oc][w0], sm[2][oc][w0]));
      mn1[oc] = fminf(fminf(mn1[oc], sm[0][oc][w0 + 1]),
                      fminf(sm[1][oc][w0 + 1], sm[2][oc][w0 + 1]));
    }
    float mx0 = mn0[0], mx1 = mn1[0];
#pragma unroll
    for (int oc = 1; oc < OCC; ++oc) {
      mx0 = fmaxf(mx0, mn0[oc]);
      mx1 = fmaxf(mx1, mn1[oc]);
    }
    float e0[OCC], e1[OCC];
    float s0 = 0.f, s1 = 0.f;
#pragma unroll
    for (int oc = 0; oc < OCC; ++oc) {
      e0[oc] = __expf(mn0[oc] - mx0); s0 += e0[oc];
      e1[oc] = __expf(mn1[oc] - mx1); s1 += e1[oc];
    }
    const float i0 = 1.f / s0;
    const float i1 = 1.f / s1;

    float* ob = out + ((size_t)b * OCC * HOUT + h) * (size_t)WOUT + w0;
    const size_t os = (size_t)HOUT * WOUT;
#pragma unroll
    for (int oc = 0; oc < OCC; ++oc) {
      float2 v;
      v.x = e0[oc] * i0;
      v.y = e1[oc] * i1;
      *reinterpret_cast<float2*>(ob + oc * os) = v;  // w0 even -> 8B aligned
    }
  }
}

extern "C" void kernel_launch(void* const* d_in, const int* in_sizes, int n_in,
                              void* d_out, int out_size, void* d_ws, size_t ws_size,
                              hipStream_t stream) {
  const float* x = (const float*)d_in[0];
  const float* wt = (const float*)d_in[1];
  float* out = (float*)d_out;
  float* wT = (float*)d_ws;  // 81*16 floats = 5184 B scratch

  wtrans_kernel<<<dim3(6), dim3(256), 0, stream>>>(wt, wT);

  dim3 grid(1008);          // 1-D: wgid&7 = batch = XCD, wgid>>3 = h
  dim3 block(256, 1, 1);    // 4 waves, dz chunks 3+3 / 3+2, Wtile=2
  conv_min_softmax_kernel<<<grid, block, 0, stream>>>(x, wT, out);
}